// Round 11
// baseline (45.562 us; speedup 1.0000x reference)
//
#include <hip/hip_runtime.h>
#include <math.h>

// densemap = sum_k c_k * log2(relu(k^2 * conv_k(x)) + 1)
// conv_k = separable Gaussian (sigma = k/2), TF-SAME padding: pad_lo = (k-1)/2.
// Column/row window offsets union: -2..+3 (6 wide). k=1 kernel == identity.
//
// Tile: 64x32 outputs per block (block 64x4, 8 rows/wave), staged 37x72 LDS.
// Single pass, minimum-depth per-kernel rings (h6[6] h5[5] h4[4] h3[4] h2[3]
// h1[3] = 25 floats). NEW in this round: every ring value is PINNED into an
// arch VGPR at each step boundary via empty asm ("+v") -- the compiler was
// rematerializing ring values from LDS (2 ds_reads + FMAs per use) instead of
// carrying them, which is why VGPR_Count sat at 24 while real VALU+LGKM ran
// ~2x the hand count. Pinning makes the carry mandatory; live set ~50 regs
// still fits the 64-reg tier of __launch_bounds__(256,8).

struct Weights {
    // horizontal symmetric-pair coefficients (prescaled by k^2)
    float h6a, h6b, h6c, h5a, h5b, h5c, h4a, h4b, h3a, h3b, h2c;
    // vertical symmetric-pair coefficients
    float v6a, v6b, v6c, v5a, v5b, v5c, v4a, v4b, v3a, v3b, v2a;
    float c[6];     // regression slope coefficients
};

#define TXO 64
#define TYO 32
#define RPT 8           // rows per thread (block 64x4)
#define LDSW 72         // floats per staged row (16B-aligned stride)
#define SROWS 37        // staged rows: outputs -2..+34
#define NF4 (SROWS * 18)  // 666 float4s per tile

#define GLOAD_LDS16(gp, lp) __builtin_amdgcn_global_load_lds( \
    (const __attribute__((address_space(1))) unsigned int*)(gp), \
    (__attribute__((address_space(3))) unsigned int*)(lp), 16, 0, 0)

__global__ __launch_bounds__(256, 8) void ldeb_kernel(const float* __restrict__ x,
                                                      float* __restrict__ out,
                                                      Weights W) {
    __shared__ float xs[SROWS * LDSW];
    const int img = blockIdx.z;
    const int bx = blockIdx.x, by = blockIdx.y;
    const int x0a = bx * TXO - 4;      // aligned staged-col base
    const int y0 = by * TYO - 2;       // staged-row base
    const float* __restrict__ xb = x + (size_t)img * 262144;
    const int tid = threadIdx.y * 64 + threadIdx.x;

    if (bx >= 1 && bx <= 6 && by >= 1 && by <= 14) {
        // interior: direct global->LDS, 16B/lane, dest linear in tid
#pragma unroll
        for (int it = 0; it < 3; ++it) {
            int i = tid + it * 256;
            if (i < NF4) {
                int row = i / 18;
                int c4 = i - row * 18;
                const float* gp = xb + (size_t)(y0 + row) * 512 + x0a + 4 * c4;
                GLOAD_LDS16(gp, &xs[i * 4]);
            }
        }
    } else {
        // border: reg-staged float4 with whole-float4 zero-fill
#pragma unroll
        for (int it = 0; it < 3; ++it) {
            int i = tid + it * 256;
            if (i < NF4) {
                int row = i / 18;
                int c4 = i - row * 18;
                int gy = y0 + row;
                int gc = x0a + 4 * c4;
                float4 v = make_float4(0.f, 0.f, 0.f, 0.f);
                if ((unsigned)gy < 512u && (unsigned)gc < 512u)
                    v = *(const float4*)(xb + (size_t)gy * 512 + gc);
                *(float4*)&xs[i * 4] = v;
            }
        }
    }
    __syncthreads();

    const int lane = threadIdx.x;        // local col 0..63
    const int Lr0 = threadIdx.y * RPT;   // this wave's staged-row base
    const float* __restrict__ base = &xs[Lr0 * LDSW + lane + 2];
    float* __restrict__ ob = out + (size_t)img * 262144
                           + (size_t)(by * TYO + Lr0) * 512 + bx * TXO + lane;

    float h6[6], h5[5], h4[4], h3[4], h2[3], h1[3];  // all indices ICEs

#define LOG1(s) __builtin_amdgcn_logf(fmaxf((s), 0.0f) + 1.0f)

// force every carried ring value to live in an arch VGPR at this point;
// makes LDS-rematerialization non-profitable for the register allocator.
#define PIN(v) asm volatile("" : "+v"(v))
#define KEEPALL { \
        PIN(h6[0]); PIN(h6[1]); PIN(h6[2]); PIN(h6[3]); PIN(h6[4]); PIN(h6[5]); \
        PIN(h5[0]); PIN(h5[1]); PIN(h5[2]); PIN(h5[3]); PIN(h5[4]); \
        PIN(h4[0]); PIN(h4[1]); PIN(h4[2]); PIN(h4[3]); \
        PIN(h3[0]); PIN(h3[1]); PIN(h3[2]); PIN(h3[3]); \
        PIN(h2[0]); PIN(h2[1]); PIN(h2[2]); \
        PIN(h1[0]); PIN(h1[1]); PIN(h1[2]); \
    }

// prologue row j = 0..4: fill rings only
#define PROW(j) { \
        const float* row = base + (j) * LDSW; \
        float v0 = row[0], v1 = row[1], v2 = row[2], \
              v3 = row[3], v4 = row[4], v5 = row[5]; \
        float s05 = v0 + v5, s14 = v1 + v4, s23 = v2 + v3; \
        float s04 = v0 + v4, s13 = v1 + v3; \
        h6[(j) % 6] = W.h6a * s05 + W.h6b * s14 + W.h6c * s23; \
        h5[(j) % 5] = W.h5a * s04 + W.h5b * s13 + W.h5c * v2; \
        h4[(j) % 4] = W.h4a * s14 + W.h4b * s23; \
        h3[(j) % 4] = W.h3a * s13 + W.h3b * v2; \
        h2[(j) % 3] = W.h2c * s23; \
        h1[(j) % 3] = v2; \
    }

// step r: read staged row r+5, emit output row r
#define STEPR(r) { \
        const float* row = base + ((r) + 5) * LDSW; \
        float v0 = row[0], v1 = row[1], v2 = row[2], \
              v3 = row[3], v4 = row[4], v5 = row[5]; \
        float s05 = v0 + v5, s14 = v1 + v4, s23 = v2 + v3; \
        float s04 = v0 + v4, s13 = v1 + v3; \
        float H6 = W.h6a * s05 + W.h6b * s14 + W.h6c * s23; \
        float t6 = W.v6a * (h6[(r) % 6] + H6) \
                 + W.v6b * (h6[((r) + 1) % 6] + h6[((r) + 4) % 6]) \
                 + W.v6c * (h6[((r) + 2) % 6] + h6[((r) + 3) % 6]); \
        float t5 = W.v5a * (h5[(r) % 5] + h5[((r) + 4) % 5]) \
                 + W.v5b * (h5[((r) + 1) % 5] + h5[((r) + 3) % 5]) \
                 + W.v5c * h5[((r) + 2) % 5]; \
        float t4 = W.v4a * (h4[((r) + 1) % 4] + h4[((r) + 4) % 4]) \
                 + W.v4b * (h4[((r) + 2) % 4] + h4[((r) + 3) % 4]); \
        float t3 = W.v3a * (h3[((r) + 1) % 4] + h3[((r) + 3) % 4]) \
                 + W.v3b * h3[((r) + 2) % 4]; \
        float t2 = W.v2a * (h2[((r) + 2) % 3] + h2[((r) + 3) % 3]); \
        float t1 = h1[((r) + 5) % 3]; /* row r+2, read before overwrite */ \
        h6[((r) + 5) % 6] = H6; \
        h5[((r) + 5) % 5] = W.h5a * s04 + W.h5b * s13 + W.h5c * v2; \
        h4[((r) + 5) % 4] = W.h4a * s14 + W.h4b * s23; \
        h3[((r) + 5) % 4] = W.h3a * s13 + W.h3b * v2; \
        h2[((r) + 5) % 3] = W.h2c * s23; \
        h1[((r) + 5) % 3] = v2; \
        float res = fmaf(W.c[5], LOG1(t6), \
                    fmaf(W.c[4], LOG1(t5), \
                    fmaf(W.c[3], LOG1(t4), \
                    fmaf(W.c[2], LOG1(t3), \
                    fmaf(W.c[1], LOG1(t2), \
                         W.c[0] * LOG1(t1)))))); \
        ob[(r) * 512] = res; \
    }

    PROW(0) KEEPALL PROW(1) KEEPALL PROW(2) KEEPALL
    PROW(3) KEEPALL PROW(4) KEEPALL
    STEPR(0) KEEPALL STEPR(1) KEEPALL STEPR(2) KEEPALL STEPR(3) KEEPALL
    STEPR(4) KEEPALL STEPR(5) KEEPALL STEPR(6) KEEPALL STEPR(7)

#undef STEPR
#undef PROW
#undef KEEPALL
#undef PIN
#undef LOG1
}

extern "C" void kernel_launch(void* const* d_in, const int* in_sizes, int n_in,
                              void* d_out, int out_size, void* d_ws, size_t ws_size,
                              hipStream_t stream) {
    const float* x = (const float*)d_in[0];
    float* out = (float*)d_out;

    Weights W;
    // regression coefficients: c_k = (X_k - mean(X)) / sum((X - mean)^2), X_k = log2(k)
    double X[6], mean = 0.0;
    for (int k = 1; k <= 6; ++k) { X[k - 1] = log2((double)k); mean += X[k - 1]; }
    mean /= 6.0;
    double denom = 0.0;
    for (int i = 0; i < 6; ++i) { double xc = X[i] - mean; denom += xc * xc; }
    for (int i = 0; i < 6; ++i) W.c[i] = (float)((X[i] - mean) / denom);

    // separable gaussian 1D weights, sigma = k/2
    float wh[6][6], wv[6][6];
    for (int k = 1; k <= 6; ++k) {
        double sigma = k / 2.0;
        double g[6], s = 0.0;
        for (int i = 0; i < k; ++i) {
            double a = i - (k - 1) / 2.0;
            g[i] = exp(-(a * a) / (2.0 * sigma * sigma));
            s += g[i];
        }
        for (int i = 0; i < 6; ++i) {
            if (i < k) {
                double gn = g[i] / s;
                wv[k - 1][i] = (float)gn;
                wh[k - 1][i] = (float)(gn * (double)(k * k)); // horizontal prescaled by k^2
            } else {
                wv[k - 1][i] = 0.0f;
                wh[k - 1][i] = 0.0f;
            }
        }
    }
    // symmetric-pair coefficients
    W.h6a = wh[5][0]; W.h6b = wh[5][1]; W.h6c = wh[5][2];
    W.h5a = wh[4][0]; W.h5b = wh[4][1]; W.h5c = wh[4][2];
    W.h4a = wh[3][0]; W.h4b = wh[3][1];
    W.h3a = wh[2][0]; W.h3b = wh[2][1];
    W.h2c = wh[1][0];
    W.v6a = wv[5][0]; W.v6b = wv[5][1]; W.v6c = wv[5][2];
    W.v5a = wv[4][0]; W.v5b = wv[4][1]; W.v5c = wv[4][2];
    W.v4a = wv[3][0]; W.v4b = wv[3][1];
    W.v3a = wv[2][0]; W.v3b = wv[2][1];
    W.v2a = wv[1][0];

    dim3 grid(512 / TXO, 512 / TYO, 64);
    dim3 block(64, 4, 1);
    hipLaunchKernelGGL(ldeb_kernel, grid, block, 0, stream, x, out, W);
}